// Round 4
// baseline (4563.965 us; speedup 1.0000x reference)
//
#include <hip/hip_runtime.h>

#define TINN 512
#define FF 64
#define HHD 512
#define TOUTN 64

using v8h = __attribute__((ext_vector_type(8))) _Float16;
using v4h = __attribute__((ext_vector_type(4))) _Float16;
using v4f = __attribute__((ext_vector_type(4))) float;
using u32x4 = __attribute__((ext_vector_type(4))) unsigned int;
using u64 = unsigned long long;

#define AGT __HIP_MEMORY_SCOPE_AGENT

// ---------------- LDS layout (bytes) ----------------
#define WOFF 0            // weights, MFMA fragment order (max 128KB)
#define BIAS_OFF 131072
#define WIH0_OFF 131328
#define PREV_OFF 131584
#define PART_OFF 131840
#define PROJW_OFF 132864
#define PROJB_OFF 134912
#define TRANS_OFF 134976  // 4 waves x 512B h-transpose scratch
#define SMEM_TOTAL 137024

// ---------------- workspace layout ----------------
// REPLICATED progress flags, then h0/h1 ring buffers.
// DEEP mode: 32-deep rings + CACHED consumer loads + agent-acquire fence
// every 24 steps. Producer stores stay cache-bypass (LLC always fresh
// before the flag). A cached line survives <= 24+skew(<=5) < 32 steps
// before its address is rewritten, so the periodic buffer_inv kills every
// potentially-stale line. Round-2 validated this protocol's correctness
// (per-step fence); here the fence cost is amortized 24x.
// Shallow mode (small ws): round-3 behavior (4-deep/2-deep + bypass loads).
#define WS_BAR 0
#define WS_FLAG_BYTES (4 * 64 * 64 * 64)   // 1 MiB
#define WS_HOFF WS_FLAG_BYTES
#define HBYTES (256 * HHD * 2)             // 256 KiB per ring slot
#define WS_NEED_DEEP (WS_FLAG_BYTES + (size_t)64 * HBYTES)   // ~17.8 MB
#define INV_PERIOD 24

static __device__ __forceinline__ float sigm(float x) { return 1.0f / (1.0f + __expf(-x)); }
static __device__ __forceinline__ float tanh_f(float x) { return 1.0f - 2.0f / (1.0f + __expf(2.0f * x)); }

static __device__ __forceinline__ v8h aload16(const _Float16* p) {
  union { u64 u[2]; v8h h; } c;
  const u64* q = (const u64*)p;
  c.u[0] = __hip_atomic_load(q, __ATOMIC_RELAXED, AGT);
  c.u[1] = __hip_atomic_load(q + 1, __ATOMIC_RELAXED, AGT);
  return c.h;
}
static __device__ __forceinline__ void astore8(_Float16* p, v4h v) {
  union { u64 u; v4h h; } c;
  c.h = v;
  __hip_atomic_store((u64*)p, c.u, __ATOMIC_RELAXED, AGT);
}
static __device__ __forceinline__ void astore8z(void* p) {
  __hip_atomic_store((u64*)p, 0ull, __ATOMIC_RELAXED, AGT);
}
static __device__ __forceinline__ void acquireFence() {
  __builtin_amdgcn_fence(__ATOMIC_ACQUIRE, "agent");   // waitcnt + buffer_inv
}

#if __has_builtin(__builtin_amdgcn_raw_ptr_buffer_load_b128) && \
    __has_builtin(__builtin_amdgcn_make_buffer_rsrc)
#define HAVE_BUFLOAD 1
using rsrc_t = __amdgpu_buffer_rsrc_t;
static __device__ __forceinline__ rsrc_t mkrsrc(const void* p) {
  return __builtin_amdgcn_make_buffer_rsrc((void*)p, (short)0, 0xFFFFFFFFu, 0x00020000);
}
static __device__ __forceinline__ v8h bload16(rsrc_t r, int byteOff) {
  union { u32x4 u; v8h h; } c;
  c.u = __builtin_amdgcn_raw_ptr_buffer_load_b128(r, byteOff, 0, 17);  // sc0|sc1
  return c.h;
}
#endif

// Producer broadcast: after all h stores are acked (waitcnt 0 + barrier),
// lanes 0..63 each store `val` into one consumer's private slot.
static __device__ __forceinline__ void signalDone(unsigned* flagsG, int mySlot, unsigned val) {
  __builtin_amdgcn_s_waitcnt(0);
  __syncthreads();
  if (threadIdx.x < 64) {
    unsigned* p = flagsG + ((size_t)threadIdx.x * 64 + mySlot) * 16;
    __hip_atomic_store(p, val, __ATOMIC_RELAXED, AGT);
  }
}

// Poll base..base+31 of THIS consumer's private slots until all >= tgt.
static __device__ __forceinline__ void waitRolePriv(unsigned* myflags, int base, int tgt) {
  if (tgt > 0) {
    if (threadIdx.x < 32) {
      unsigned* p = myflags + (size_t)(base + threadIdx.x) * 16;
      while ((int)__hip_atomic_load(p, __ATOMIC_RELAXED, AGT) < tgt)
        __builtin_amdgcn_s_sleep(1);
    }
    __syncthreads();
#if __has_builtin(__builtin_amdgcn_sched_barrier)
    __builtin_amdgcn_sched_barrier(0);
#endif
  }
}

// Dual-role poll on private slots: lanes 0-31 poll role0 (tgt0), lanes
// 32-63 poll role1 (tgt1). tgt <= 0 skips that role.
static __device__ __forceinline__ void waitRolesPriv(unsigned* myflags, int tgt0, int tgt1) {
  int t = threadIdx.x;
  if (t < 64) {
    int tgt = (t < 32) ? tgt0 : tgt1;
    if (tgt > 0) {
      unsigned* p = myflags + (size_t)t * 16;
      while ((int)__hip_atomic_load(p, __ATOMIC_RELAXED, AGT) < tgt)
        __builtin_amdgcn_s_sleep(1);
    }
  }
  __syncthreads();
#if __has_builtin(__builtin_amdgcn_sched_barrier)
  __builtin_amdgcn_sched_barrier(0);
#endif
}

// Weight slice (64 gate-cols x K) fp32->fp16 into LDS, fragment order.
static __device__ __attribute__((noinline)) void loadWeights(
    int tid, int hc0, const float* W1, int ld1, int K1,
    const float* W2, int K) {
  extern __shared__ char smem[];
  int c = tid >> 2, sub = tid & 3;
  int nt = c >> 4, l = c & 15;
  int n = nt * HHD + hc0 + l;
  int Kq = K >> 2;
  for (int k = sub * Kq; k < (sub + 1) * Kq; ++k) {
    float v;
    if (k < K1) v = W1[(size_t)n * ld1 + k];
    else        v = W2[(size_t)n * HHD + (k - K1)];
    int kc = k >> 6, ks = (k >> 5) & 1, quad = (k >> 3) & 3, j = k & 7;
    int off = (((kc * 2 + ks) * 4 + nt) * 64 + quad * 16 + l) * 16 + j * 2;
    *(_Float16*)(smem + WOFF + off) = (_Float16)v;
  }
}

// 8 K-chunks of MFMA from swizzled src, weight chunks WC0..WC0+7.
// DEEP: plain cached loads (L1+L2 allocate; freshness by ring+periodic inv).
// Shallow: LLC-bypass loads.
template <int WC0, bool DEEP>
static __device__ __forceinline__ void mfma8(
    const _Float16* src, int rt, int lane, const char* wbLane, v4f* acc) {
#if HAVE_BUFLOAD
  rsrc_t rs;
  if constexpr (!DEEP) rs = mkrsrc(src);
#endif
#pragma unroll
  for (int kc = 0; kc < 8; ++kc) {
    int off = rt * 16384 + kc * 2048 + lane * 16;
    v8h ak0, ak1;
    if constexpr (DEEP) {
      ak0 = *(const v8h*)((const char*)src + off);
      ak1 = *(const v8h*)((const char*)src + off + 1024);
    } else {
#if HAVE_BUFLOAD
      ak0 = bload16(rs, off);
      ak1 = bload16(rs, off + 1024);
#else
      ak0 = aload16(src + off / 2);
      ak1 = aload16(src + (off + 1024) / 2);
#endif
    }
    const char* bb = wbLane + (size_t)(WC0 + kc) * 8192;
#pragma unroll
    for (int ks = 0; ks < 2; ++ks) {
      v8h a = ks ? ak1 : ak0;
      acc[0] = __builtin_amdgcn_mfma_f32_16x16x32_f16(a, *(const v8h*)(bb + (ks * 4 + 0) * 1024), acc[0], 0, 0, 0);
      acc[1] = __builtin_amdgcn_mfma_f32_16x16x32_f16(a, *(const v8h*)(bb + (ks * 4 + 1) * 1024), acc[1], 0, 0, 0);
      acc[2] = __builtin_amdgcn_mfma_f32_16x16x32_f16(a, *(const v8h*)(bb + (ks * 4 + 2) * 1024), acc[2], 0, 0, 0);
      acc[3] = __builtin_amdgcn_mfma_f32_16x16x32_f16(a, *(const v8h*)(bb + (ks * 4 + 3) * 1024), acc[3], 0, 0, 0);
    }
  }
}

// Fused double-source MFMA for stepL1: all 32 A-loads (h1 then h0) issued
// before any MFMA. h1 -> weight chunks 8..15, h0 -> weight chunks 0..7.
template <bool DEEP>
static __device__ __forceinline__ void mfmaDual(
    const _Float16* h0src, const _Float16* h1src, int rt, int lane,
    const char* wbLane, v4f* acc) {
  v8h a1[16], a0[16];
  if constexpr (DEEP) {
#pragma unroll
    for (int kc = 0; kc < 8; ++kc) {
      int off = rt * 16384 + kc * 2048 + lane * 16;
      a1[2 * kc]     = *(const v8h*)((const char*)h1src + off);
      a1[2 * kc + 1] = *(const v8h*)((const char*)h1src + off + 1024);
    }
#pragma unroll
    for (int kc = 0; kc < 8; ++kc) {
      int off = rt * 16384 + kc * 2048 + lane * 16;
      a0[2 * kc]     = *(const v8h*)((const char*)h0src + off);
      a0[2 * kc + 1] = *(const v8h*)((const char*)h0src + off + 1024);
    }
  } else {
#if HAVE_BUFLOAD
    rsrc_t r1 = mkrsrc(h1src);
    rsrc_t r0 = mkrsrc(h0src);
#pragma unroll
    for (int kc = 0; kc < 8; ++kc) {
      int off = rt * 16384 + kc * 2048 + lane * 16;
      a1[2 * kc]     = bload16(r1, off);
      a1[2 * kc + 1] = bload16(r1, off + 1024);
    }
#pragma unroll
    for (int kc = 0; kc < 8; ++kc) {
      int off = rt * 16384 + kc * 2048 + lane * 16;
      a0[2 * kc]     = bload16(r0, off);
      a0[2 * kc + 1] = bload16(r0, off + 1024);
    }
#else
#pragma unroll
    for (int kc = 0; kc < 8; ++kc) {
      int off = rt * 16384 + kc * 2048 + lane * 16;
      a1[2 * kc]     = aload16(h1src + off / 2);
      a1[2 * kc + 1] = aload16(h1src + (off + 1024) / 2);
    }
#pragma unroll
    for (int kc = 0; kc < 8; ++kc) {
      int off = rt * 16384 + kc * 2048 + lane * 16;
      a0[2 * kc]     = aload16(h0src + off / 2);
      a0[2 * kc + 1] = aload16(h0src + (off + 1024) / 2);
    }
#endif
  }
#pragma unroll
  for (int kc = 0; kc < 8; ++kc) {
    const char* bb = wbLane + (size_t)(8 + kc) * 8192;
#pragma unroll
    for (int ks = 0; ks < 2; ++ks) {
      v8h a = a1[2 * kc + ks];
      acc[0] = __builtin_amdgcn_mfma_f32_16x16x32_f16(a, *(const v8h*)(bb + (ks * 4 + 0) * 1024), acc[0], 0, 0, 0);
      acc[1] = __builtin_amdgcn_mfma_f32_16x16x32_f16(a, *(const v8h*)(bb + (ks * 4 + 1) * 1024), acc[1], 0, 0, 0);
      acc[2] = __builtin_amdgcn_mfma_f32_16x16x32_f16(a, *(const v8h*)(bb + (ks * 4 + 2) * 1024), acc[2], 0, 0, 0);
      acc[3] = __builtin_amdgcn_mfma_f32_16x16x32_f16(a, *(const v8h*)(bb + (ks * 4 + 3) * 1024), acc[3], 0, 0, 0);
    }
  }
#pragma unroll
  for (int kc = 0; kc < 8; ++kc) {
    const char* bb = wbLane + (size_t)kc * 8192;
#pragma unroll
    for (int ks = 0; ks < 2; ++ks) {
      v8h a = a0[2 * kc + ks];
      acc[0] = __builtin_amdgcn_mfma_f32_16x16x32_f16(a, *(const v8h*)(bb + (ks * 4 + 0) * 1024), acc[0], 0, 0, 0);
      acc[1] = __builtin_amdgcn_mfma_f32_16x16x32_f16(a, *(const v8h*)(bb + (ks * 4 + 1) * 1024), acc[1], 0, 0, 0);
      acc[2] = __builtin_amdgcn_mfma_f32_16x16x32_f16(a, *(const v8h*)(bb + (ks * 4 + 2) * 1024), acc[2], 0, 0, 0);
      acc[3] = __builtin_amdgcn_mfma_f32_16x16x32_f16(a, *(const v8h*)(bb + (ks * 4 + 3) * 1024), acc[3], 0, 0, 0);
    }
  }
}

// x chunk (weight chunk 0): raw fp32 x, cached (read-only -> inv-safe).
static __device__ __forceinline__ void xChunk(
    const float* xstep, int m0, int tid, const char* wbLane, v4f* acc) {
  int lane = tid & 63, wave = tid >> 6;
  int l15 = lane & 15, quad = lane >> 4;
  v8h ak0, ak1;
  int ra = m0 + wave * 16 + l15;
  const float* xr = xstep + (size_t)ra * (TINN * FF) + quad * 8;
  v4f f00 = *(const v4f*)(xr);
  v4f f01 = *(const v4f*)(xr + 4);
  v4f f10 = *(const v4f*)(xr + 32);
  v4f f11 = *(const v4f*)(xr + 36);
#pragma unroll
  for (int e = 0; e < 4; ++e) {
    ak0[e] = (_Float16)f00[e]; ak0[4 + e] = (_Float16)f01[e];
    ak1[e] = (_Float16)f10[e]; ak1[4 + e] = (_Float16)f11[e];
  }
#pragma unroll
  for (int ks = 0; ks < 2; ++ks) {
    v8h a = ks ? ak1 : ak0;
    acc[0] = __builtin_amdgcn_mfma_f32_16x16x32_f16(a, *(const v8h*)(wbLane + (ks * 4 + 0) * 1024), acc[0], 0, 0, 0);
    acc[1] = __builtin_amdgcn_mfma_f32_16x16x32_f16(a, *(const v8h*)(wbLane + (ks * 4 + 1) * 1024), acc[1], 0, 0, 0);
    acc[2] = __builtin_amdgcn_mfma_f32_16x16x32_f16(a, *(const v8h*)(wbLane + (ks * 4 + 2) * 1024), acc[2], 0, 0, 0);
    acc[3] = __builtin_amdgcn_mfma_f32_16x16x32_f16(a, *(const v8h*)(wbLane + (ks * 4 + 3) * 1024), acc[3], 0, 0, 0);
  }
}

// In-register gate math + per-wave LDS mini-transpose for a coalesced 8B
// h write (bypass store: fresh at LLC before the flag).
static __device__ __forceinline__ void epilogue(
    int tid, int m0, int hc0, int rank1, _Float16* hout, float* creg, v4f* acc) {
  extern __shared__ char smem[];
  int lane = tid & 63, wave = tid >> 6;
  int l15 = lane & 15, quad = lane >> 4;
  float* bias = (float*)(smem + BIAS_OFF);
  float bi = bias[l15], bf = bias[16 + l15], bg = bias[32 + l15], bo = bias[48 + l15];
  float wi = 0.f, wf = 0.f, wg = 0.f, wo = 0.f;
  if (rank1) {
    float* wih0 = (float*)(smem + WIH0_OFF);
    wi = wih0[l15]; wf = wih0[16 + l15]; wg = wih0[32 + l15]; wo = wih0[48 + l15];
  }
  float* prevl = (float*)(smem + PREV_OFF);
  _Float16* tb = (_Float16*)(smem + TRANS_OFF + (size_t)wave * 512);
#pragma unroll
  for (int r = 0; r < 4; ++r) {
    int mloc = wave * 16 + quad * 4 + r;
    float gi = acc[0][r] + bi, gf = acc[1][r] + bf;
    float gg = acc[2][r] + bg, go = acc[3][r] + bo;
    if (rank1) {
      float pv = prevl[mloc];
      gi += pv * wi; gf += pv * wf; gg += pv * wg; go += pv * wo;
    }
    float cc = sigm(gf) * creg[r] + sigm(gi) * tanh_f(gg);
    float h = sigm(go) * tanh_f(cc);
    creg[r] = cc;
    tb[(quad * 4 + r) * 16 + l15] = (_Float16)h;   // m-fast deposit
  }
  {
    int mloc = lane & 15, cg = lane >> 4;
    v4h hv = *(const v4h*)(tb + mloc * 16 + cg * 4);
    int m = m0 + wave * 16 + mloc;
    int c0 = hc0 + cg * 4;
    int off = (m >> 4) * 16384 + (c0 >> 6) * 2048 + ((c0 >> 5) & 1) * 1024 +
              ((c0 >> 3) & 3) * 256 + (m & 15) * 16 + (c0 & 7) * 2;
    astore8((_Float16*)((char*)hout + off), hv);
  }
}

// ---- step functions ----

template <bool DEEP>
static __device__ __attribute__((noinline)) void stepEnc0(
    int tid, int m0, int hc0, unsigned* flagsG, unsigned* myflags, int mySlot, int p,
    const float* xstep, const _Float16* h0prev, _Float16* h0out, float* creg,
    bool doInv) {
  extern __shared__ char smem[];
  int lane = tid & 63, wave = tid >> 6;
  v4f acc[4];
  acc[0] = v4f{0.f, 0.f, 0.f, 0.f}; acc[1] = acc[0]; acc[2] = acc[0]; acc[3] = acc[0];
  const char* wbLane = smem + WOFF + (size_t)lane * 16;
  xChunk(xstep, m0, tid, wbLane, acc);          // off critical path
  waitRolesPriv(myflags, p + 1, p - 2);         // h0(p-1) ready + reuse guard
  if (DEEP && doInv) acquireFence();
  mfma8<1, DEEP>(h0prev, (m0 >> 4) + wave, lane, wbLane, acc);
  epilogue(tid, m0, hc0, 0, h0out, creg, acc);
  signalDone(flagsG, mySlot, p + 2);
}

template <bool DEEP>
static __device__ __attribute__((noinline)) void stepL1(
    int tid, int m0, int hc0, unsigned* flagsG, unsigned* myflags, int mySlot,
    int tR1, int tR0,
    const _Float16* h0src, const _Float16* h1prev, _Float16* h1out, float* creg,
    bool doInv) {
  extern __shared__ char smem[];
  int lane = tid & 63, wave = tid >> 6;
  v4f acc[4];
  acc[0] = v4f{0.f, 0.f, 0.f, 0.f}; acc[1] = acc[0]; acc[2] = acc[0]; acc[3] = acc[0];
  const char* wbLane = smem + WOFF + (size_t)lane * 16;
  int rt = (m0 >> 4) + wave;
  waitRolesPriv(myflags, tR0, tR1);   // h0(cur) + h1(prev)+reuse, one poll
  if (DEEP && doInv) acquireFence();
  mfmaDual<DEEP>(h0src, h1prev, rt, lane, wbLane, acc);
  epilogue(tid, m0, hc0, 0, h1out, creg, acc);
  signalDone(flagsG, mySlot, tR0);
}

template <bool DEEP>
static __device__ __attribute__((noinline)) void stepDec0(
    int tid, int m0, int hc0, unsigned* flagsG, unsigned* myflags, int mySlot, int u,
    const _Float16* h0prev, _Float16* h0out, float* creg, bool doInv) {
  extern __shared__ char smem[];
  int lane = tid & 63, wave = tid >> 6;
  v4f acc[4];
  acc[0] = v4f{0.f, 0.f, 0.f, 0.f}; acc[1] = acc[0]; acc[2] = acc[0]; acc[3] = acc[0];
  const char* wbLane = smem + WOFF + (size_t)lane * 16;
  waitRolePriv(myflags, 0, u + 1);    // h0(t-1) ready (own role)
  if (DEEP && doInv) acquireFence();
  mfma8<0, DEEP>(h0prev, (m0 >> 4) + wave, lane, wbLane, acc);
  epilogue(tid, m0, hc0, 1, h0out, creg, acc);
  signalDone(flagsG, mySlot, u + 2);
}

template <bool DEEP>
__global__ void __launch_bounds__(256, 1)
seq2seq_kernel(const float* x,
               const float* e0wi, const float* e0wh, const float* e0bi, const float* e0bh,
               const float* e1wi, const float* e1wh, const float* e1bi, const float* e1bh,
               const float* d0wi, const float* d0wh, const float* d0bi, const float* d0bh,
               const float* d1wi, const float* d1wh, const float* d1bi, const float* d1bh,
               const float* pw, const float* pb,
               float* out, char* ws) {
  extern __shared__ char smem[];
  constexpr int D0M = DEEP ? 31 : 3;   // h0 ring mask
  constexpr int D1M = DEEP ? 31 : 1;   // h1 ring mask
  int tid = threadIdx.x, bid = blockIdx.x;
  int group = bid >> 6;
  int r = bid & 63;
  bool isL1 = (r >= 32);
  int hcTile = r & 31;
  int hc0 = hcTile * 16;
  int m0 = group * 64;
  unsigned* flagsG = (unsigned*)(ws + WS_BAR) + (size_t)group * 64 * 64 * 16;
  unsigned* myflags = flagsG + (size_t)r * 64 * 16;
  int mySlot = isL1 ? 32 + hcTile : hcTile;

  char* h0ring = ws + WS_HOFF;
  char* h1ring = ws + WS_HOFF + (size_t)(D0M + 1) * HBYTES;

  float creg[4];
  creg[0] = 0.f; creg[1] = 0.f; creg[2] = 0.f; creg[3] = 0.f;

  // zero the "step -1" ring slots (h0 slot D0M, h1 slot D1M), group slice
  {
    int t16 = r * 256 + tid;
    char* base = (t16 < 8192) ? (h0ring + (size_t)D0M * HBYTES)
                              : (h1ring + (size_t)D1M * HBYTES);
    int idx = t16 & 8191;
    astore8z(base + (size_t)m0 * HHD * 2 + (size_t)idx * 8);
  }

  if (!isL1) {
    loadWeights(tid, hc0, e0wi, 64, 64, e0wh, 576);
    if (tid < 64) {
      int n = (tid >> 4) * HHD + hc0 + (tid & 15);
      ((float*)(smem + BIAS_OFF))[tid] = e0bi[n] + e0bh[n];
    }
  } else {
    loadWeights(tid, hc0, e1wi, 512, 512, e1wh, 1024);
    if (tid < 64) {
      int n = (tid >> 4) * HHD + hc0 + (tid & 15);
      ((float*)(smem + BIAS_OFF))[tid] = e1bi[n] + e1bh[n];
    }
  }
  signalDone(flagsG, mySlot, 1);

  if (!isL1) {
    // ---------------- encoder layer 0 ----------------
    for (int p = 0; p < TINN; ++p)
      stepEnc0<DEEP>(tid, m0, hc0, flagsG, myflags, mySlot, p,
                     x + (size_t)p * FF,
                     (const _Float16*)(h0ring + (size_t)((p + D0M) & D0M) * HBYTES),
                     (_Float16*)(h0ring + (size_t)(p & D0M) * HBYTES),
                     creg, (p % INV_PERIOD) == 0);
    // ---------------- decoder layer 0 ----------------
    loadWeights(tid, hc0, d0wh, 512, 512, nullptr, 512);
    if (tid < 64) {
      int n = (tid >> 4) * HHD + hc0 + (tid & 15);
      ((float*)(smem + BIAS_OFF))[tid] = d0bi[n] + d0bh[n];
      ((float*)(smem + WIH0_OFF))[tid] = d0wi[n];
    }
    for (int k = tid; k < 512; k += 256) ((float*)(smem + PROJW_OFF))[k] = pw[k];
    if (tid == 0) ((float*)(smem + PROJB_OFF))[0] = pb[0];
    for (int t = 0; t <= TOUTN; ++t) {
      int u = TINN + t;
      waitRolePriv(myflags, 32, u + 1);   // h1(t-1) ready
      float* prevl = (float*)(smem + PREV_OFF);
      if (t == 0) {
        if (tid < 64)
          prevl[tid] = x[(size_t)(m0 + tid) * (TINN * FF) + 511 * 64 + 63];
      } else {
        float* part = (float*)(smem + PART_OFF);
        float* pjw = (float*)(smem + PROJW_OFF);
        const _Float16* h1base =
            (const _Float16*)(h1ring + (size_t)((u + D1M) & D1M) * HBYTES);
        int m = m0 + (tid >> 2);
        int rt = m >> 4, l15m = m & 15;
        int kc0 = (tid & 3) * 2;
        float s = 0.f;
#pragma unroll
        for (int kc = kc0; kc < kc0 + 2; ++kc)
#pragma unroll
          for (int ks = 0; ks < 2; ++ks)
#pragma unroll
            for (int q = 0; q < 4; ++q) {
              int off = (rt * 8 + kc) * 2048 + ks * 1024 + q * 256 + l15m * 16;
              v8h hv = aload16(h1base + off / 2);
              const float* w = pjw + kc * 64 + ks * 32 + q * 8;
#pragma unroll
              for (int e = 0; e < 8; ++e) s += (float)hv[e] * w[e];
            }
        part[tid] = s;
        __syncthreads();
        if (tid < 64) {
          float p4 = part[tid * 4] + part[tid * 4 + 1] + part[tid * 4 + 2] +
                     part[tid * 4 + 3] + ((float*)(smem + PROJB_OFF))[0];
          prevl[tid] = p4;
          if (hcTile == 0) out[(size_t)(m0 + tid) * TOUTN + (t - 1)] = p4;
        }
      }
      __syncthreads();
      if (t < TOUTN)
        stepDec0<DEEP>(tid, m0, hc0, flagsG, myflags, mySlot, u,
                       (const _Float16*)(h0ring + (size_t)((u + D0M) & D0M) * HBYTES),
                       (_Float16*)(h0ring + (size_t)(u & D0M) * HBYTES),
                       creg, (u % INV_PERIOD) == 0);
    }
  } else {
    // ---------------- encoder layer 1 ----------------
    for (int s = 0; s < TINN; ++s)
      stepL1<DEEP>(tid, m0, hc0, flagsG, myflags, mySlot, s + 1, s + 2,
                   (const _Float16*)(h0ring + (size_t)(s & D0M) * HBYTES),
                   (const _Float16*)(h1ring + (size_t)((s + D1M) & D1M) * HBYTES),
                   (_Float16*)(h1ring + (size_t)(s & D1M) * HBYTES),
                   creg, (s % INV_PERIOD) == 0);
    // ---------------- decoder layer 1 ----------------
    loadWeights(tid, hc0, d1wi, 512, 512, d1wh, 1024);
    if (tid < 64) {
      int n = (tid >> 4) * HHD + hc0 + (tid & 15);
      ((float*)(smem + BIAS_OFF))[tid] = d1bi[n] + d1bh[n];
    }
    for (int t = 0; t < TOUTN; ++t) {
      int u = TINN + t;
      stepL1<DEEP>(tid, m0, hc0, flagsG, myflags, mySlot, u + 1, u + 2,
                   (const _Float16*)(h0ring + (size_t)(u & D0M) * HBYTES),
                   (const _Float16*)(h1ring + (size_t)((u + D1M) & D1M) * HBYTES),
                   (_Float16*)(h1ring + (size_t)(u & D1M) * HBYTES),
                   creg, (u % INV_PERIOD) == 0);
    }
  }
}

extern "C" void kernel_launch(void* const* d_in, const int* in_sizes, int n_in,
                              void* d_out, int out_size, void* d_ws, size_t ws_size,
                              hipStream_t stream) {
  const float* x = (const float*)d_in[0];
  const float* e0wi = (const float*)d_in[2];
  const float* e0wh = (const float*)d_in[3];
  const float* e0bi = (const float*)d_in[4];
  const float* e0bh = (const float*)d_in[5];
  const float* e1wi = (const float*)d_in[6];
  const float* e1wh = (const float*)d_in[7];
  const float* e1bi = (const float*)d_in[8];
  const float* e1bh = (const float*)d_in[9];
  const float* d0wi = (const float*)d_in[10];
  const float* d0wh = (const float*)d_in[11];
  const float* d0bi = (const float*)d_in[12];
  const float* d0bh = (const float*)d_in[13];
  const float* d1wi = (const float*)d_in[14];
  const float* d1wh = (const float*)d_in[15];
  const float* d1bi = (const float*)d_in[16];
  const float* d1bh = (const float*)d_in[17];
  const float* pw = (const float*)d_in[18];
  const float* pb = (const float*)d_in[19];

  bool deep = (ws_size >= WS_NEED_DEEP);
  (void)hipMemsetAsync(d_ws, 0, WS_FLAG_BYTES, stream);  // replicated flags
  if (deep) {
    (void)hipFuncSetAttribute((const void*)seq2seq_kernel<true>,
                              hipFuncAttributeMaxDynamicSharedMemorySize, SMEM_TOTAL);
    seq2seq_kernel<true><<<dim3(256), dim3(256), SMEM_TOTAL, stream>>>(
        x, e0wi, e0wh, e0bi, e0bh, e1wi, e1wh, e1bi, e1bh,
        d0wi, d0wh, d0bi, d0bh, d1wi, d1wh, d1bi, d1bh,
        pw, pb, (float*)d_out, (char*)d_ws);
  } else {
    (void)hipFuncSetAttribute((const void*)seq2seq_kernel<false>,
                              hipFuncAttributeMaxDynamicSharedMemorySize, SMEM_TOTAL);
    seq2seq_kernel<false><<<dim3(256), dim3(256), SMEM_TOTAL, stream>>>(
        x, e0wi, e0wh, e0bi, e0bh, e1wi, e1wh, e1bi, e1bh,
        d0wi, d0wh, d0bi, d0bh, d1wi, d1wh, d1bi, d1bh,
        pw, pb, (float*)d_out, (char*)d_ws);
  }
}